// Round 1
// baseline (808.012 us; speedup 1.0000x reference)
//
#include <hip/hip_runtime.h>

#define NN 50000
#define NE 800000
#define FIN 500
#define DH 128
#define NC 10

// ---------------- setup kernels ----------------

__global__ void init_kernel(float* __restrict__ deg, int* __restrict__ count, int n) {
    int i = blockIdx.x * blockDim.x + threadIdx.x;
    if (i < n) { deg[i] = 1.0f; count[i] = 0; }   // deg starts at 1.0 (self-loop weight)
}

__global__ void deg_count_kernel(const int* __restrict__ ei, const float* __restrict__ w,
                                 float* __restrict__ deg, int* __restrict__ count, int e) {
    int i = blockIdx.x * blockDim.x + threadIdx.x;
    if (i < e) {
        int d = ei[NE + i];               // dst row of edge_index
        atomicAdd(&deg[d], w[i]);
        atomicAdd(&count[d], 1);
    }
}

__global__ void dinv_kernel(float* __restrict__ deg, int n) {
    int i = blockIdx.x * blockDim.x + threadIdx.x;
    if (i < n) deg[i] = rsqrtf(deg[i]);   // deg >= 1 always (self-loop), in-place -> dinv
}

// single-block exclusive scan over count[n] -> rowptr, cursor
__global__ void scan_kernel(const int* __restrict__ count, int* __restrict__ rowptr,
                            int* __restrict__ cursor, int n, int total) {
    __shared__ int swave[16];
    int t = threadIdx.x;
    int lane = t & 63, wid = t >> 6;
    int base = 0;
    for (int start = 0; start < n; start += 1024) {
        int idx = start + t;
        int v = (idx < n) ? count[idx] : 0;
        int x = v;
        #pragma unroll
        for (int off = 1; off < 64; off <<= 1) {
            int y = __shfl_up(x, off, 64);
            if (lane >= off) x += y;
        }
        if (lane == 63) swave[wid] = x;
        __syncthreads();
        if (wid == 0) {
            int s = (lane < 16) ? swave[lane] : 0;
            #pragma unroll
            for (int off = 1; off < 16; off <<= 1) {
                int y = __shfl_up(s, off, 64);
                if (lane >= off) s += y;
            }
            if (lane < 16) swave[lane] = s;
        }
        __syncthreads();
        int wbase = (wid > 0) ? swave[wid - 1] : 0;
        int excl = base + wbase + (x - v);
        if (idx < n) { rowptr[idx] = excl; cursor[idx] = excl; }
        int ctot = swave[15];
        __syncthreads();            // protect swave before next chunk overwrites
        base += ctot;
    }
    if (t == 0) rowptr[n] = total;
}

__global__ void scatter_kernel(const int* __restrict__ ei, const float* __restrict__ w,
                               const float* __restrict__ dinv, int* __restrict__ cursor,
                               int* __restrict__ csr_src, float* __restrict__ csr_norm, int e) {
    int i = blockIdx.x * blockDim.x + threadIdx.x;
    if (i < e) {
        int s = ei[i];
        int d = ei[NE + i];
        int pos = atomicAdd(&cursor[d], 1);
        csr_src[pos] = s;
        csr_norm[pos] = dinv[s] * w[i] * dinv[d];
    }
}

// ---------------- dense MM: C[M][128] = A[M][K] @ B[K][128] ----------------
// BM=64, BN=128, BK=32, 256 threads, 8x4 register tile per thread.

__global__ __launch_bounds__(256)
void mm_kernel(const float* __restrict__ A, const float* __restrict__ B,
               float* __restrict__ C, int M, int K) {
    __shared__ float AsT[32 * 68];    // k-major, pad to 68 (rows 272B -> 16B aligned)
    __shared__ float Bs[32 * 128];
    int t = threadIdx.x;
    int tcol = t & 31;                // cols tcol*4 .. +3
    int trow = t >> 5;                // rows trow*8 .. +7
    int row0 = blockIdx.x * 64;
    float acc[8][4] = {};

    for (int k0 = 0; k0 < K; k0 += 32) {
        // stage A tile (64 rows x 32 k), coalesced reads, k-major writes
        #pragma unroll
        for (int i = 0; i < 8; ++i) {
            int idx = i * 256 + t;
            int k = idx & 31, m = idx >> 5;
            int grow = row0 + m, gk = k0 + k;
            float v = 0.f;
            if (grow < M && gk < K) v = A[(long)grow * K + gk];
            AsT[k * 68 + m] = v;
        }
        // stage B tile (32 k x 128 cols), float4
        #pragma unroll
        for (int i = 0; i < 4; ++i) {
            int idx = i * 256 + t;
            int k = idx >> 5, c4 = (idx & 31) * 4;
            float4 v = make_float4(0.f, 0.f, 0.f, 0.f);
            int gk = k0 + k;
            if (gk < K) v = *(const float4*)&B[gk * 128 + c4];
            *(float4*)&Bs[k * 128 + c4] = v;
        }
        __syncthreads();
        #pragma unroll 8
        for (int kk = 0; kk < 32; ++kk) {
            float4 a0 = *(const float4*)&AsT[kk * 68 + trow * 8];
            float4 a1 = *(const float4*)&AsT[kk * 68 + trow * 8 + 4];
            float4 b  = *(const float4*)&Bs[kk * 128 + tcol * 4];
            float av[8] = {a0.x, a0.y, a0.z, a0.w, a1.x, a1.y, a1.z, a1.w};
            float bv[4] = {b.x, b.y, b.z, b.w};
            #pragma unroll
            for (int r = 0; r < 8; ++r)
                #pragma unroll
                for (int c = 0; c < 4; ++c)
                    acc[r][c] += av[r] * bv[c];
        }
        __syncthreads();
    }
    #pragma unroll
    for (int r = 0; r < 8; ++r) {
        int row = row0 + trow * 8 + r;
        if (row < M)
            *(float4*)&C[(long)row * 128 + tcol * 4] =
                make_float4(acc[r][0], acc[r][1], acc[r][2], acc[r][3]);
    }
}

// ---------------- aggregation: out[i] = relu(b + dinv[i]^2*h[i] + sum norm*h[src]) ----------------
// 256 threads = 2 nodes/block, 128 threads (features) per node.

__global__ __launch_bounds__(256)
void agg_kernel(const float* __restrict__ h, const int* __restrict__ rowptr,
                const int* __restrict__ csr_src, const float* __restrict__ csr_norm,
                const float* __restrict__ dinv, const float* __restrict__ bias,
                float* __restrict__ out, int n) {
    int node = blockIdx.x * 2 + (threadIdx.x >> 7);
    int f = threadIdx.x & 127;
    if (node >= n) return;
    float di = dinv[node];
    float acc = di * di * h[(long)node * DH + f];   // self-loop
    int e0 = rowptr[node], e1 = rowptr[node + 1];
    for (int e = e0; e < e1; ++e) {
        int s = csr_src[e];
        float nm = csr_norm[e];
        acc += nm * h[(long)s * DH + f];
    }
    acc += bias[f];
    out[(long)node * DH + f] = fmaxf(acc, 0.f);
}

// ---------------- classifier: out[N][10] = H[N][128] @ Wc[128][10] + bc ----------------
// one wave per row, shuffle reduction

__global__ __launch_bounds__(256)
void cls_kernel(const float* __restrict__ H, const float* __restrict__ Wc,
                const float* __restrict__ bc, float* __restrict__ out, int n) {
    int lane = threadIdx.x & 63;
    int gw = (blockIdx.x * blockDim.x + threadIdx.x) >> 6;
    int nw = (gridDim.x * blockDim.x) >> 6;
    float wl[NC], wh[NC];
    #pragma unroll
    for (int c = 0; c < NC; ++c) {
        wl[c] = Wc[lane * NC + c];
        wh[c] = Wc[(lane + 64) * NC + c];
    }
    float bcv = (lane < NC) ? bc[lane] : 0.f;
    for (int row = gw; row < n; row += nw) {
        float hl = H[(long)row * DH + lane];
        float hh = H[(long)row * DH + 64 + lane];
        float myval = 0.f;
        #pragma unroll
        for (int c = 0; c < NC; ++c) {
            float p = hl * wl[c] + hh * wh[c];
            #pragma unroll
            for (int off = 32; off; off >>= 1) p += __shfl_xor(p, off, 64);
            if (lane == c) myval = p;
        }
        if (lane < NC) out[(long)row * NC + lane] = myval + bcv;
    }
}

// ---------------- launch ----------------

extern "C" void kernel_launch(void* const* d_in, const int* in_sizes, int n_in,
                              void* d_out, int out_size, void* d_ws, size_t ws_size,
                              hipStream_t stream) {
    const float* x  = (const float*)d_in[0];
    const int*   ei = (const int*)d_in[1];
    const float* ew = (const float*)d_in[2];
    const float* W1 = (const float*)d_in[3];
    const float* b1 = (const float*)d_in[4];
    const float* W2 = (const float*)d_in[5];
    const float* b2 = (const float*)d_in[6];
    const float* Wc = (const float*)d_in[7];
    const float* bc = (const float*)d_in[8];
    float* out = (float*)d_out;

    char* ws = (char*)d_ws;
    size_t off = 0;
    auto alloc = [&](size_t bytes) { char* p = ws + off; off += (bytes + 255) & ~255ULL; return p; };
    float* deg      = (float*)alloc(NN * 4);        // becomes dinv in-place
    int*   count    = (int*)  alloc(NN * 4);
    int*   rowptr   = (int*)  alloc((NN + 1) * 4);
    int*   cursor   = (int*)  alloc(NN * 4);
    int*   csr_src  = (int*)  alloc(NE * 4);
    float* csr_norm = (float*)alloc(NE * 4);
    float* bufA     = (float*)alloc((size_t)NN * DH * 4);
    float* bufB     = (float*)alloc((size_t)NN * DH * 4);

    int bn = (NN + 255) / 256;
    int be = (NE + 255) / 256;

    init_kernel<<<bn, 256, 0, stream>>>(deg, count, NN);
    deg_count_kernel<<<be, 256, 0, stream>>>(ei, ew, deg, count, NE);
    dinv_kernel<<<bn, 256, 0, stream>>>(deg, NN);
    scan_kernel<<<1, 1024, 0, stream>>>(count, rowptr, cursor, NN, NE);
    scatter_kernel<<<be, 256, 0, stream>>>(ei, ew, deg, cursor, csr_src, csr_norm, NE);

    // layer 1: h1 = x @ W1 ; agg+bias+relu
    mm_kernel<<<(NN + 63) / 64, 256, 0, stream>>>(x, W1, bufA, NN, FIN);
    agg_kernel<<<(NN + 1) / 2, 256, 0, stream>>>(bufA, rowptr, csr_src, csr_norm, deg, b1, bufB, NN);

    // layer 2: h2 = h1' @ W2 ; agg+bias+relu
    mm_kernel<<<(NN + 63) / 64, 256, 0, stream>>>(bufB, W2, bufA, NN, DH);
    agg_kernel<<<(NN + 1) / 2, 256, 0, stream>>>(bufA, rowptr, csr_src, csr_norm, deg, b2, bufB, NN);

    // classifier
    cls_kernel<<<512, 256, 0, stream>>>(bufB, Wc, bc, out, NN);
}

// Round 2
// 562.100 us; speedup vs baseline: 1.4375x; 1.4375x over previous
//
#include <hip/hip_runtime.h>

#define NN 50000
#define NE 800000
#define FIN 500
#define DH 128
#define NC 10

// ---------------- setup kernels ----------------

__global__ void init_kernel(float* __restrict__ deg, int* __restrict__ count, int n) {
    int i = blockIdx.x * blockDim.x + threadIdx.x;
    if (i < n) { deg[i] = 1.0f; count[i] = 0; }   // deg starts at 1.0 (self-loop weight)
}

__global__ void deg_count_kernel(const int* __restrict__ ei, const float* __restrict__ w,
                                 float* __restrict__ deg, int* __restrict__ count, int e) {
    int i = blockIdx.x * blockDim.x + threadIdx.x;
    if (i < e) {
        int d = ei[NE + i];               // dst row of edge_index
        atomicAdd(&deg[d], w[i]);
        atomicAdd(&count[d], 1);
    }
}

__global__ void dinv_kernel(float* __restrict__ deg, int n) {
    int i = blockIdx.x * blockDim.x + threadIdx.x;
    if (i < n) deg[i] = rsqrtf(deg[i]);   // deg >= 1 always (self-loop), in-place -> dinv
}

// ---- 3-phase scan: count[n] -> rowptr (exclusive), cursor copy ----
// phase1: 49 blocks x 256 thr, 4 elems/thread, block-relative exclusive + block sums
__global__ void scan1_kernel(const int* __restrict__ count, int* __restrict__ rp,
                             int* __restrict__ bsum, int n) {
    __shared__ int sw[4];
    int t = threadIdx.x, lane = t & 63, w = t >> 6;
    int base = blockIdx.x * 1024 + t * 4;
    int c0 = (base + 0 < n) ? count[base + 0] : 0;
    int c1 = (base + 1 < n) ? count[base + 1] : 0;
    int c2 = (base + 2 < n) ? count[base + 2] : 0;
    int c3 = (base + 3 < n) ? count[base + 3] : 0;
    int s0 = c0, s1 = s0 + c1, s2 = s1 + c2, s3 = s2 + c3;
    int x = s3;                                   // inclusive scan of thread sums over wave
    #pragma unroll
    for (int off = 1; off < 64; off <<= 1) {
        int y = __shfl_up(x, off, 64);
        if (lane >= off) x += y;
    }
    if (lane == 63) sw[w] = x;
    __syncthreads();
    int woff = 0;
    for (int j = 0; j < w; ++j) woff += sw[j];
    int excl = woff + x - s3;                      // block-relative exclusive before elem 0
    if (base + 0 < n) rp[base + 0] = excl;
    if (base + 1 < n) rp[base + 1] = excl + s0;
    if (base + 2 < n) rp[base + 2] = excl + s1;
    if (base + 3 < n) rp[base + 3] = excl + s2;
    if (t == 255) bsum[blockIdx.x] = woff + x;     // block total
}

// phase2: one wave scans block sums -> exclusive offsets (in-place)
__global__ void scan2_kernel(int* __restrict__ bsum, int nb) {
    int lane = threadIdx.x;
    int v = (lane < nb) ? bsum[lane] : 0;
    int x = v;
    #pragma unroll
    for (int off = 1; off < 64; off <<= 1) {
        int y = __shfl_up(x, off, 64);
        if (lane >= off) x += y;
    }
    if (lane < nb) bsum[lane] = x - v;             // exclusive
}

// phase3: add block offsets, write cursor copy, set rowptr[n]
__global__ void scan3_kernel(int* __restrict__ rp, int* __restrict__ cursor,
                             const int* __restrict__ bsum, int n) {
    int i = blockIdx.x * blockDim.x + threadIdx.x;
    if (i < n) {
        int v = rp[i] + bsum[i >> 10];
        rp[i] = v;
        cursor[i] = v;
    }
    if (i == 0) rp[n] = NE;
}

__global__ void scatter_kernel(const int* __restrict__ ei, const float* __restrict__ w,
                               const float* __restrict__ dinv, int* __restrict__ cursor,
                               int* __restrict__ csr_src, float* __restrict__ csr_norm, int e) {
    int i = blockIdx.x * blockDim.x + threadIdx.x;
    if (i < e) {
        int s = ei[i];
        int d = ei[NE + i];
        int pos = atomicAdd(&cursor[d], 1);
        csr_src[pos] = s;
        csr_norm[pos] = dinv[s] * w[i] * dinv[d];
    }
}

// ---------------- dense MM: P[z] = A[M][K] @ B[K][128] (K split over gridDim.z) ----
// 128x128 tile, BK=32, 256 threads, 8x8 register tile. Ratio FMA:LDS-inst = 16.

__global__ __launch_bounds__(256, 4)
void mm8x8_kernel(const float* __restrict__ A, const float* __restrict__ B,
                  float* __restrict__ P, int M, int K) {
    __shared__ float As[32 * 132];    // [k][m], pad 132 keeps b128 reads aligned
    __shared__ float Bs[32 * 128];    // [k][col swizzled: even/odd float4 groups split]
    const int t = threadIdx.x;
    const int tcol = t & 15;          // 16 col-groups of 8
    const int trow = t >> 4;          // 16 row-groups of 8
    const int row0 = blockIdx.x * 128;
    const int KC = (K + 31) >> 5;
    const int per = KC / gridDim.z;   // gridDim.z divides KC for our shapes
    const int cbeg = blockIdx.z * per;
    float* __restrict__ Pz = P + (size_t)blockIdx.z * ((size_t)M * DH);

    float acc[8][8];
    #pragma unroll
    for (int r = 0; r < 8; ++r)
        #pragma unroll
        for (int c = 0; c < 8; ++c) acc[r][c] = 0.f;

    for (int ch = 0; ch < per; ++ch) {
        const int k0 = (cbeg + ch) << 5;
        // stage A: 128 rows x 32 k = 1024 float4 (K is a multiple of 4: no straddle)
        #pragma unroll
        for (int i = 0; i < 4; ++i) {
            int idx = i * 256 + t;
            int m = idx >> 3, g = idx & 7;
            int gr = row0 + m, gk = k0 + g * 4;
            float4 v = make_float4(0.f, 0.f, 0.f, 0.f);
            if (gr < M && gk < K) v = *(const float4*)&A[gr * K + gk];
            As[(g * 4 + 0) * 132 + m] = v.x;
            As[(g * 4 + 1) * 132 + m] = v.y;
            As[(g * 4 + 2) * 132 + m] = v.z;
            As[(g * 4 + 3) * 132 + m] = v.w;
        }
        // stage B: 32 k x 128 cols, swizzle group g -> ((g&1)<<6)|((g>>1)<<2)
        #pragma unroll
        for (int i = 0; i < 4; ++i) {
            int idx = i * 256 + t;
            int k = idx >> 5, g = idx & 31;
            int gk = k0 + k;
            float4 v = make_float4(0.f, 0.f, 0.f, 0.f);
            if (gk < K) v = *(const float4*)&B[gk * DH + g * 4];
            int slot = ((g & 1) << 6) | ((g >> 1) << 2);
            *(float4*)&Bs[k * 128 + slot] = v;
        }
        __syncthreads();
        #pragma unroll 8
        for (int kk = 0; kk < 32; ++kk) {
            float4 a0 = *(const float4*)&As[kk * 132 + trow * 8];
            float4 a1 = *(const float4*)&As[kk * 132 + trow * 8 + 4];
            float4 b0 = *(const float4*)&Bs[kk * 128 + tcol * 4];        // cols tcol*8+0..3
            float4 b1 = *(const float4*)&Bs[kk * 128 + 64 + tcol * 4];   // cols tcol*8+4..7
            float av[8] = {a0.x, a0.y, a0.z, a0.w, a1.x, a1.y, a1.z, a1.w};
            float bv[8] = {b0.x, b0.y, b0.z, b0.w, b1.x, b1.y, b1.z, b1.w};
            #pragma unroll
            for (int r = 0; r < 8; ++r)
                #pragma unroll
                for (int c = 0; c < 8; ++c)
                    acc[r][c] = fmaf(av[r], bv[c], acc[r][c]);
        }
        __syncthreads();
    }
    #pragma unroll
    for (int r = 0; r < 8; ++r) {
        int row = row0 + trow * 8 + r;
        if (row < M) {
            float* o = Pz + (size_t)row * DH + tcol * 8;
            *(float4*)&o[0] = make_float4(acc[r][0], acc[r][1], acc[r][2], acc[r][3]);
            *(float4*)&o[4] = make_float4(acc[r][4], acc[r][5], acc[r][6], acc[r][7]);
        }
    }
}

// in-place combine: p0 += p1 (+ p2 + p3 when S>2)
__global__ void combine_kernel(float4* __restrict__ p0, const float4* __restrict__ p1,
                               const float4* __restrict__ p2, const float4* __restrict__ p3,
                               int n4, int S) {
    int stride = gridDim.x * blockDim.x;
    for (int i = blockIdx.x * blockDim.x + threadIdx.x; i < n4; i += stride) {
        float4 a = p0[i], b = p1[i];
        a.x += b.x; a.y += b.y; a.z += b.z; a.w += b.w;
        if (S > 2) {
            float4 c = p2[i], d = p3[i];
            a.x += c.x + d.x; a.y += c.y + d.y; a.z += c.z + d.z; a.w += c.w + d.w;
        }
        p0[i] = a;
    }
}

// ---------------- aggregation: wave per node, float2 per lane ----------------

__global__ __launch_bounds__(256)
void agg_kernel(const float* __restrict__ h, const int* __restrict__ rowptr,
                const int* __restrict__ csr_src, const float* __restrict__ csr_norm,
                const float* __restrict__ dinv, const float* __restrict__ bias,
                float* __restrict__ out, int n) {
    int node = (blockIdx.x * 256 + threadIdx.x) >> 6;
    if (node >= n) return;
    int lane = threadIdx.x & 63;
    float di = dinv[node];
    float2 hv = *(const float2*)&h[node * DH + lane * 2];
    float ax = di * di * hv.x, ay = di * di * hv.y;
    int e = rowptr[node], e1 = rowptr[node + 1];
    for (; e + 4 <= e1; e += 4) {
        int s0 = csr_src[e], s1 = csr_src[e + 1], s2 = csr_src[e + 2], s3 = csr_src[e + 3];
        float n0 = csr_norm[e], n1 = csr_norm[e + 1], n2 = csr_norm[e + 2], n3 = csr_norm[e + 3];
        float2 v0 = *(const float2*)&h[s0 * DH + lane * 2];
        float2 v1 = *(const float2*)&h[s1 * DH + lane * 2];
        float2 v2 = *(const float2*)&h[s2 * DH + lane * 2];
        float2 v3 = *(const float2*)&h[s3 * DH + lane * 2];
        ax = fmaf(n0, v0.x, ax); ay = fmaf(n0, v0.y, ay);
        ax = fmaf(n1, v1.x, ax); ay = fmaf(n1, v1.y, ay);
        ax = fmaf(n2, v2.x, ax); ay = fmaf(n2, v2.y, ay);
        ax = fmaf(n3, v3.x, ax); ay = fmaf(n3, v3.y, ay);
    }
    for (; e < e1; ++e) {
        int s = csr_src[e];
        float nm = csr_norm[e];
        float2 v = *(const float2*)&h[s * DH + lane * 2];
        ax = fmaf(nm, v.x, ax); ay = fmaf(nm, v.y, ay);
    }
    ax += bias[lane * 2];
    ay += bias[lane * 2 + 1];
    float2 o = make_float2(fmaxf(ax, 0.f), fmaxf(ay, 0.f));
    *(float2*)&out[node * DH + lane * 2] = o;
}

// agg + classifier fused: h2 row stays in registers, out = relu(agg) @ Wc + bc
__global__ __launch_bounds__(256)
void agg_cls_kernel(const float* __restrict__ h, const int* __restrict__ rowptr,
                    const int* __restrict__ csr_src, const float* __restrict__ csr_norm,
                    const float* __restrict__ dinv, const float* __restrict__ bias,
                    const float* __restrict__ Wc, const float* __restrict__ bc,
                    float* __restrict__ out, int n) {
    int node = (blockIdx.x * 256 + threadIdx.x) >> 6;
    if (node >= n) return;
    int lane = threadIdx.x & 63;
    float di = dinv[node];
    float2 hv = *(const float2*)&h[node * DH + lane * 2];
    float ax = di * di * hv.x, ay = di * di * hv.y;
    int e = rowptr[node], e1 = rowptr[node + 1];
    for (; e + 4 <= e1; e += 4) {
        int s0 = csr_src[e], s1 = csr_src[e + 1], s2 = csr_src[e + 2], s3 = csr_src[e + 3];
        float n0 = csr_norm[e], n1 = csr_norm[e + 1], n2 = csr_norm[e + 2], n3 = csr_norm[e + 3];
        float2 v0 = *(const float2*)&h[s0 * DH + lane * 2];
        float2 v1 = *(const float2*)&h[s1 * DH + lane * 2];
        float2 v2 = *(const float2*)&h[s2 * DH + lane * 2];
        float2 v3 = *(const float2*)&h[s3 * DH + lane * 2];
        ax = fmaf(n0, v0.x, ax); ay = fmaf(n0, v0.y, ay);
        ax = fmaf(n1, v1.x, ax); ay = fmaf(n1, v1.y, ay);
        ax = fmaf(n2, v2.x, ax); ay = fmaf(n2, v2.y, ay);
        ax = fmaf(n3, v3.x, ax); ay = fmaf(n3, v3.y, ay);
    }
    for (; e < e1; ++e) {
        int s = csr_src[e];
        float nm = csr_norm[e];
        float2 v = *(const float2*)&h[s * DH + lane * 2];
        ax = fmaf(nm, v.x, ax); ay = fmaf(nm, v.y, ay);
    }
    float hx = fmaxf(ax + bias[lane * 2], 0.f);
    float hy = fmaxf(ay + bias[lane * 2 + 1], 0.f);
    // classifier: p[c] = sum over features; features 2*lane, 2*lane+1 on this lane
    float myv = 0.f;
    #pragma unroll
    for (int c = 0; c < NC; ++c) {
        float p = hx * Wc[(2 * lane) * NC + c] + hy * Wc[(2 * lane + 1) * NC + c];
        p += __shfl_xor(p, 32, 64);
        p += __shfl_xor(p, 16, 64);
        p += __shfl_xor(p, 8, 64);
        p += __shfl_xor(p, 4, 64);
        p += __shfl_xor(p, 2, 64);
        p += __shfl_xor(p, 1, 64);
        if (lane == c) myv = p;
    }
    if (lane < NC) out[node * NC + lane] = myv + bc[lane];
}

// ---------------- launch ----------------

extern "C" void kernel_launch(void* const* d_in, const int* in_sizes, int n_in,
                              void* d_out, int out_size, void* d_ws, size_t ws_size,
                              hipStream_t stream) {
    const float* x  = (const float*)d_in[0];
    const int*   ei = (const int*)d_in[1];
    const float* ew = (const float*)d_in[2];
    const float* W1 = (const float*)d_in[3];
    const float* b1 = (const float*)d_in[4];
    const float* W2 = (const float*)d_in[5];
    const float* b2 = (const float*)d_in[6];
    const float* Wc = (const float*)d_in[7];
    const float* bc = (const float*)d_in[8];
    float* out = (float*)d_out;

    char* ws = (char*)d_ws;
    size_t off = 0;
    auto alloc = [&](size_t bytes) { char* p = ws + off; off += (bytes + 255) & ~255ULL; return p; };
    float* deg      = (float*)alloc(NN * 4);        // becomes dinv in-place
    int*   count    = (int*)  alloc(NN * 4);
    int*   rowptr   = (int*)  alloc((NN + 1) * 4);
    int*   cursor   = (int*)  alloc(NN * 4);
    int*   bsum     = (int*)  alloc(64 * 4);
    int*   csr_src  = (int*)  alloc(NE * 4);
    float* csr_norm = (float*)alloc(NE * 4);

    const size_t F = (size_t)NN * DH * sizeof(float);
    // P0..P{S1-1} must be CONTIGUOUS (mm kernel offsets by blockIdx.z * M * DH)
    float* P0 = (float*)alloc(F);
    float* P1 = nullptr; float* P2 = nullptr; float* P3 = nullptr;
    int S1 = 1;
    if (ws_size >= off + 4 * F + 4096) {            // P1..P3 + H2
        P1 = (float*)alloc(F); P2 = (float*)alloc(F); P3 = (float*)alloc(F); S1 = 4;
    } else if (ws_size >= off + 2 * F + 4096) {     // P1 + H2
        P1 = (float*)alloc(F); S1 = 2;
    }
    float* H2 = (float*)alloc(F);
    int S2 = (S1 >= 2) ? 2 : 1;                     // mm2 partials go to P0,P1 (input is H2)

    init_kernel<<<(NN + 255) / 256, 256, 0, stream>>>(deg, count, NN);
    deg_count_kernel<<<(NE + 255) / 256, 256, 0, stream>>>(ei, ew, deg, count, NE);
    dinv_kernel<<<(NN + 255) / 256, 256, 0, stream>>>(deg, NN);
    scan1_kernel<<<(NN + 1023) / 1024, 256, 0, stream>>>(count, rowptr, bsum, NN);
    scan2_kernel<<<1, 64, 0, stream>>>(bsum, (NN + 1023) / 1024);
    scan3_kernel<<<(NN + 255) / 256, 256, 0, stream>>>(rowptr, cursor, bsum, NN);
    scatter_kernel<<<(NE + 255) / 256, 256, 0, stream>>>(ei, ew, deg, cursor, csr_src, csr_norm, NE);

    const int n4 = NN * DH / 4;
    // layer 1: h1 = x @ W1 (split-K), combine, then agg+bias+relu
    mm8x8_kernel<<<dim3((NN + 127) / 128, 1, S1), 256, 0, stream>>>(x, W1, P0, NN, FIN);
    if (S1 > 1)
        combine_kernel<<<2048, 256, 0, stream>>>((float4*)P0, (const float4*)P1,
                                                 (const float4*)P2, (const float4*)P3, n4, S1);
    agg_kernel<<<(NN * 64 + 255) / 256, 256, 0, stream>>>(P0, rowptr, csr_src, csr_norm,
                                                          deg, b1, H2, NN);
    // layer 2: h2 = h1' @ W2 (split-K into P0,P1), combine, then fused agg+relu+classifier
    mm8x8_kernel<<<dim3((NN + 127) / 128, 1, S2), 256, 0, stream>>>(H2, W2, P0, NN, DH);
    if (S2 > 1)
        combine_kernel<<<2048, 256, 0, stream>>>((float4*)P0, (const float4*)P1,
                                                 (const float4*)P1, (const float4*)P1, n4, S2);
    agg_cls_kernel<<<(NN * 64 + 255) / 256, 256, 0, stream>>>(P0, rowptr, csr_src, csr_norm,
                                                              deg, b2, Wc, bc, out, NN);
}

// Round 3
// 559.415 us; speedup vs baseline: 1.4444x; 1.0048x over previous
//
#include <hip/hip_runtime.h>

#define NN 50000
#define NE 800000
#define FIN 500
#define DH 128
#define NC 10

typedef __attribute__((ext_vector_type(8))) short short8v;   // 8 bf16 (4 VGPRs)
typedef __attribute__((ext_vector_type(4))) float float4v;   // MFMA C/D

__device__ __forceinline__ ushort f32_bf16_rne(float f) {
    uint u = __float_as_uint(f);
    uint r = u + 0x7FFFu + ((u >> 16) & 1u);
    return (ushort)(r >> 16);
}

// ---------------- setup kernels ----------------

__global__ void init_kernel(float* __restrict__ deg, int* __restrict__ count, int n) {
    int i = blockIdx.x * blockDim.x + threadIdx.x;
    if (i < n) { deg[i] = 1.0f; count[i] = 0; }   // deg starts at 1.0 (self-loop weight)
}

__global__ void deg_count_kernel(const int* __restrict__ ei, const float* __restrict__ w,
                                 float* __restrict__ deg, int* __restrict__ count, int e) {
    int i = blockIdx.x * blockDim.x + threadIdx.x;
    if (i < e) {
        int d = ei[NE + i];               // dst row of edge_index
        atomicAdd(&deg[d], w[i]);
        atomicAdd(&count[d], 1);
    }
}

__global__ void dinv_kernel(float* __restrict__ deg, int n) {
    int i = blockIdx.x * blockDim.x + threadIdx.x;
    if (i < n) deg[i] = rsqrtf(deg[i]);   // deg >= 1 always (self-loop), in-place -> dinv
}

// ---- 3-phase scan: count[n] -> rowptr (exclusive), cursor copy ----
__global__ void scan1_kernel(const int* __restrict__ count, int* __restrict__ rp,
                             int* __restrict__ bsum, int n) {
    __shared__ int sw[4];
    int t = threadIdx.x, lane = t & 63, w = t >> 6;
    int base = blockIdx.x * 1024 + t * 4;
    int c0 = (base + 0 < n) ? count[base + 0] : 0;
    int c1 = (base + 1 < n) ? count[base + 1] : 0;
    int c2 = (base + 2 < n) ? count[base + 2] : 0;
    int c3 = (base + 3 < n) ? count[base + 3] : 0;
    int s0 = c0, s1 = s0 + c1, s2 = s1 + c2, s3 = s2 + c3;
    int x = s3;
    #pragma unroll
    for (int off = 1; off < 64; off <<= 1) {
        int y = __shfl_up(x, off, 64);
        if (lane >= off) x += y;
    }
    if (lane == 63) sw[w] = x;
    __syncthreads();
    int woff = 0;
    for (int j = 0; j < w; ++j) woff += sw[j];
    int excl = woff + x - s3;
    if (base + 0 < n) rp[base + 0] = excl;
    if (base + 1 < n) rp[base + 1] = excl + s0;
    if (base + 2 < n) rp[base + 2] = excl + s1;
    if (base + 3 < n) rp[base + 3] = excl + s2;
    if (t == 255) bsum[blockIdx.x] = woff + x;
}

__global__ void scan2_kernel(int* __restrict__ bsum, int nb) {
    int lane = threadIdx.x;
    int v = (lane < nb) ? bsum[lane] : 0;
    int x = v;
    #pragma unroll
    for (int off = 1; off < 64; off <<= 1) {
        int y = __shfl_up(x, off, 64);
        if (lane >= off) x += y;
    }
    if (lane < nb) bsum[lane] = x - v;
}

__global__ void scan3_kernel(int* __restrict__ rp, int* __restrict__ cursor,
                             const int* __restrict__ bsum, int n) {
    int i = blockIdx.x * blockDim.x + threadIdx.x;
    if (i < n) {
        int v = rp[i] + bsum[i >> 10];
        rp[i] = v;
        cursor[i] = v;
    }
    if (i == 0) rp[n] = NE;
}

__global__ void scatter_kernel(const int* __restrict__ ei, const float* __restrict__ w,
                               const float* __restrict__ dinv, int* __restrict__ cursor,
                               int* __restrict__ csr_src, float* __restrict__ csr_norm, int e) {
    int i = blockIdx.x * blockDim.x + threadIdx.x;
    if (i < e) {
        int s = ei[i];
        int d = ei[NE + i];
        int pos = atomicAdd(&cursor[d], 1);
        csr_src[pos] = s;
        csr_norm[pos] = dinv[s] * w[i] * dinv[d];
    }
}

// ---- prep: W[K][128] -> Wt_hi/Wt_lo bf16 [128][Kp] (transposed, k-contiguous, 0-padded)
__global__ void prep_w_kernel(const float* __restrict__ W, ushort* __restrict__ Th,
                              ushort* __restrict__ Tl, int K, int kps) {
    int idx = blockIdx.x * blockDim.x + threadIdx.x;
    int Kp = 1 << kps;
    if (idx >= 128 * Kp) return;
    int col = idx >> kps;
    int k = idx & (Kp - 1);
    float v = (k < K) ? W[k * DH + col] : 0.f;
    ushort h = f32_bf16_rne(v);
    float hf = __uint_as_float((uint)h << 16);
    ushort l = f32_bf16_rne(v - hf);
    Th[idx] = h;
    Tl[idx] = l;
}

// ---------------- MFMA matmul: C[M][128] = A[M][K] @ B[K][128] -------------
// bf16x3 split product, fp32 accumulate. One wave per 16 output rows.
// A operand (16x16x32): lane holds A[row=lane&15][k=(lane>>4)*8 + 0..7]
// B operand:            lane holds B[k=(lane>>4)*8 + 0..7][col=lane&15]  (from Wt, k-contig)
// C/D:                  lane holds D[row=(lane>>4)*4 + reg][col=lane&15]   [m89-verified]

template<int A_SPLIT>
__global__ __launch_bounds__(256)
void mm_mfma_kernel(const float* __restrict__ Af,
                    const ushort* __restrict__ Ah, const ushort* __restrict__ Al,
                    const ushort* __restrict__ Bh, const ushort* __restrict__ Bl,
                    float* __restrict__ C, int M, int K, int Kp) {
    int gwave = (blockIdx.x * 256 + threadIdx.x) >> 6;
    int lane = threadIdx.x & 63;
    int lrow = lane & 15, lk = lane >> 4;
    int row0 = gwave * 16;

    float4v acc[8];
    #pragma unroll
    for (int c = 0; c < 8; ++c) acc[c] = (float4v){0.f, 0.f, 0.f, 0.f};

    int arow = row0 + lrow;
    if (arow > M - 1) arow = M - 1;          // clamp (stores are guarded)

    for (int k0 = 0; k0 < K; k0 += 32) {
        int kb = k0 + lk * 8;
        short8v a_hi, a_lo;
        if (A_SPLIT) {
            a_hi = *(const short8v*)(Ah + (size_t)arow * Kp + kb);
            a_lo = *(const short8v*)(Al + (size_t)arow * Kp + kb);
        } else {
            float f[8];
            if (arow == M - 1 && kb + 8 > K) {       // avoid OOB read past buffer end
                #pragma unroll
                for (int j = 0; j < 8; ++j)
                    f[j] = (kb + j < K) ? Af[(size_t)arow * K + kb + j] : 0.f;
            } else {
                float4 t0 = *(const float4*)(Af + (size_t)arow * K + kb);
                float4 t1 = *(const float4*)(Af + (size_t)arow * K + kb + 4);
                f[0] = t0.x; f[1] = t0.y; f[2] = t0.z; f[3] = t0.w;
                f[4] = t1.x; f[5] = t1.y; f[6] = t1.z; f[7] = t1.w;
            }
            // k >= K contributes 0 via zero-padded B, so garbage f is harmless
            #pragma unroll
            for (int j = 0; j < 8; ++j) {
                ushort h = f32_bf16_rne(f[j]);
                float hf = __uint_as_float((uint)h << 16);
                ushort l = f32_bf16_rne(f[j] - hf);
                a_hi[j] = (short)h;
                a_lo[j] = (short)l;
            }
        }
        #pragma unroll
        for (int c = 0; c < 8; ++c) {
            size_t boff = (size_t)(c * 16 + lrow) * Kp + kb;
            short8v bh = *(const short8v*)(Bh + boff);
            short8v bl = *(const short8v*)(Bl + boff);
            acc[c] = __builtin_amdgcn_mfma_f32_16x16x32_bf16(a_hi, bh, acc[c], 0, 0, 0);
            acc[c] = __builtin_amdgcn_mfma_f32_16x16x32_bf16(a_hi, bl, acc[c], 0, 0, 0);
            acc[c] = __builtin_amdgcn_mfma_f32_16x16x32_bf16(a_lo, bh, acc[c], 0, 0, 0);
        }
    }
    #pragma unroll
    for (int c = 0; c < 8; ++c) {
        #pragma unroll
        for (int j = 0; j < 4; ++j) {
            int r = row0 + lk * 4 + j;
            if (r < M) C[(size_t)r * DH + c * 16 + lrow] = acc[c][j];
        }
    }
}

// ---------------- aggregation: wave per node, float2 per lane ----------------
// out (layer1) written as bf16 hi/lo so mm2 skips conversion.

__global__ __launch_bounds__(256)
void agg_bf16_kernel(const float* __restrict__ h, const int* __restrict__ rowptr,
                     const int* __restrict__ csr_src, const float* __restrict__ csr_norm,
                     const float* __restrict__ dinv, const float* __restrict__ bias,
                     ushort* __restrict__ oh, ushort* __restrict__ ol, int n) {
    int node = (blockIdx.x * 256 + threadIdx.x) >> 6;
    if (node >= n) return;
    int lane = threadIdx.x & 63;
    float di = dinv[node];
    float2 hv = *(const float2*)&h[node * DH + lane * 2];
    float ax = di * di * hv.x, ay = di * di * hv.y;
    int e = rowptr[node], e1 = rowptr[node + 1];
    for (; e + 4 <= e1; e += 4) {
        int s0 = csr_src[e], s1 = csr_src[e + 1], s2 = csr_src[e + 2], s3 = csr_src[e + 3];
        float n0 = csr_norm[e], n1 = csr_norm[e + 1], n2 = csr_norm[e + 2], n3 = csr_norm[e + 3];
        float2 v0 = *(const float2*)&h[s0 * DH + lane * 2];
        float2 v1 = *(const float2*)&h[s1 * DH + lane * 2];
        float2 v2 = *(const float2*)&h[s2 * DH + lane * 2];
        float2 v3 = *(const float2*)&h[s3 * DH + lane * 2];
        ax = fmaf(n0, v0.x, ax); ay = fmaf(n0, v0.y, ay);
        ax = fmaf(n1, v1.x, ax); ay = fmaf(n1, v1.y, ay);
        ax = fmaf(n2, v2.x, ax); ay = fmaf(n2, v2.y, ay);
        ax = fmaf(n3, v3.x, ax); ay = fmaf(n3, v3.y, ay);
    }
    for (; e < e1; ++e) {
        int s = csr_src[e];
        float nm = csr_norm[e];
        float2 v = *(const float2*)&h[s * DH + lane * 2];
        ax = fmaf(nm, v.x, ax); ay = fmaf(nm, v.y, ay);
    }
    float hx = fmaxf(ax + bias[lane * 2], 0.f);
    float hy = fmaxf(ay + bias[lane * 2 + 1], 0.f);
    ushort hxh = f32_bf16_rne(hx);
    ushort hyh = f32_bf16_rne(hy);
    ushort hxl = f32_bf16_rne(hx - __uint_as_float((uint)hxh << 16));
    ushort hyl = f32_bf16_rne(hy - __uint_as_float((uint)hyh << 16));
    *(ushort2*)&oh[node * DH + lane * 2] = make_ushort2(hxh, hyh);
    *(ushort2*)&ol[node * DH + lane * 2] = make_ushort2(hxl, hyl);
}

// agg + classifier fused: h2 row stays in registers, out = relu(agg) @ Wc + bc
__global__ __launch_bounds__(256)
void agg_cls_kernel(const float* __restrict__ h, const int* __restrict__ rowptr,
                    const int* __restrict__ csr_src, const float* __restrict__ csr_norm,
                    const float* __restrict__ dinv, const float* __restrict__ bias,
                    const float* __restrict__ Wc, const float* __restrict__ bc,
                    float* __restrict__ out, int n) {
    int node = (blockIdx.x * 256 + threadIdx.x) >> 6;
    if (node >= n) return;
    int lane = threadIdx.x & 63;
    float di = dinv[node];
    float2 hv = *(const float2*)&h[node * DH + lane * 2];
    float ax = di * di * hv.x, ay = di * di * hv.y;
    int e = rowptr[node], e1 = rowptr[node + 1];
    for (; e + 4 <= e1; e += 4) {
        int s0 = csr_src[e], s1 = csr_src[e + 1], s2 = csr_src[e + 2], s3 = csr_src[e + 3];
        float n0 = csr_norm[e], n1 = csr_norm[e + 1], n2 = csr_norm[e + 2], n3 = csr_norm[e + 3];
        float2 v0 = *(const float2*)&h[s0 * DH + lane * 2];
        float2 v1 = *(const float2*)&h[s1 * DH + lane * 2];
        float2 v2 = *(const float2*)&h[s2 * DH + lane * 2];
        float2 v3 = *(const float2*)&h[s3 * DH + lane * 2];
        ax = fmaf(n0, v0.x, ax); ay = fmaf(n0, v0.y, ay);
        ax = fmaf(n1, v1.x, ax); ay = fmaf(n1, v1.y, ay);
        ax = fmaf(n2, v2.x, ax); ay = fmaf(n2, v2.y, ay);
        ax = fmaf(n3, v3.x, ax); ay = fmaf(n3, v3.y, ay);
    }
    for (; e < e1; ++e) {
        int s = csr_src[e];
        float nm = csr_norm[e];
        float2 v = *(const float2*)&h[s * DH + lane * 2];
        ax = fmaf(nm, v.x, ax); ay = fmaf(nm, v.y, ay);
    }
    float hx = fmaxf(ax + bias[lane * 2], 0.f);
    float hy = fmaxf(ay + bias[lane * 2 + 1], 0.f);
    float myv = 0.f;
    #pragma unroll
    for (int c = 0; c < NC; ++c) {
        float p = hx * Wc[(2 * lane) * NC + c] + hy * Wc[(2 * lane + 1) * NC + c];
        p += __shfl_xor(p, 32, 64);
        p += __shfl_xor(p, 16, 64);
        p += __shfl_xor(p, 8, 64);
        p += __shfl_xor(p, 4, 64);
        p += __shfl_xor(p, 2, 64);
        p += __shfl_xor(p, 1, 64);
        if (lane == c) myv = p;
    }
    if (lane < NC) out[node * NC + lane] = myv + bc[lane];
}

// ---------------- launch ----------------

extern "C" void kernel_launch(void* const* d_in, const int* in_sizes, int n_in,
                              void* d_out, int out_size, void* d_ws, size_t ws_size,
                              hipStream_t stream) {
    const float* x  = (const float*)d_in[0];
    const int*   ei = (const int*)d_in[1];
    const float* ew = (const float*)d_in[2];
    const float* W1 = (const float*)d_in[3];
    const float* b1 = (const float*)d_in[4];
    const float* W2 = (const float*)d_in[5];
    const float* b2 = (const float*)d_in[6];
    const float* Wc = (const float*)d_in[7];
    const float* bc = (const float*)d_in[8];
    float* out = (float*)d_out;

    char* ws = (char*)d_ws;
    size_t off = 0;
    auto alloc = [&](size_t bytes) { char* p = ws + off; off += (bytes + 255) & ~255ULL; return p; };
    float*  deg      = (float*)alloc(NN * 4);        // becomes dinv in-place
    int*    count    = (int*)  alloc(NN * 4);
    int*    rowptr   = (int*)  alloc((NN + 1) * 4);
    int*    cursor   = (int*)  alloc(NN * 4);
    int*    bsum     = (int*)  alloc(64 * 4);
    int*    csr_src  = (int*)  alloc(NE * 4);
    float*  csr_norm = (float*)alloc(NE * 4);
    ushort* Wt1h     = (ushort*)alloc(128 * 512 * 2);
    ushort* Wt1l     = (ushort*)alloc(128 * 512 * 2);
    ushort* Wt2h     = (ushort*)alloc(128 * 128 * 2);
    ushort* Wt2l     = (ushort*)alloc(128 * 128 * 2);
    float*  P0       = (float*)alloc((size_t)NN * DH * 4);
    ushort* H2h      = (ushort*)alloc((size_t)NN * DH * 2);
    ushort* H2l      = (ushort*)alloc((size_t)NN * DH * 2);

    init_kernel<<<(NN + 255) / 256, 256, 0, stream>>>(deg, count, NN);
    deg_count_kernel<<<(NE + 255) / 256, 256, 0, stream>>>(ei, ew, deg, count, NE);
    dinv_kernel<<<(NN + 255) / 256, 256, 0, stream>>>(deg, NN);
    scan1_kernel<<<(NN + 1023) / 1024, 256, 0, stream>>>(count, rowptr, bsum, NN);
    scan2_kernel<<<1, 64, 0, stream>>>(bsum, (NN + 1023) / 1024);
    scan3_kernel<<<(NN + 255) / 256, 256, 0, stream>>>(rowptr, cursor, bsum, NN);
    scatter_kernel<<<(NE + 255) / 256, 256, 0, stream>>>(ei, ew, deg, cursor, csr_src, csr_norm, NE);
    prep_w_kernel<<<(128 * 512 + 255) / 256, 256, 0, stream>>>(W1, Wt1h, Wt1l, FIN, 9);
    prep_w_kernel<<<(128 * 128 + 255) / 256, 256, 0, stream>>>(W2, Wt2h, Wt2l, DH, 7);

    // waves = ceil(NN/16) = 3125 -> 782 blocks of 4 waves
    int mm_blocks = ((NN + 15) / 16 + 3) / 4;

    // layer 1: h1 = x @ W1 (MFMA bf16x3), then agg+bias+relu -> bf16 hi/lo
    mm_mfma_kernel<0><<<mm_blocks, 256, 0, stream>>>(x, nullptr, nullptr, Wt1h, Wt1l,
                                                     P0, NN, FIN, 512);
    agg_bf16_kernel<<<(NN * 64 + 255) / 256, 256, 0, stream>>>(P0, rowptr, csr_src, csr_norm,
                                                               deg, b1, H2h, H2l, NN);
    // layer 2: h2 = h1 @ W2 (MFMA, A pre-split), then fused agg+relu+classifier
    mm_mfma_kernel<1><<<mm_blocks, 256, 0, stream>>>(nullptr, H2h, H2l, Wt2h, Wt2l,
                                                     P0, NN, DH, 128);
    agg_cls_kernel<<<(NN * 64 + 255) / 256, 256, 0, stream>>>(P0, rowptr, csr_src, csr_norm,
                                                              deg, b2, Wc, bc, out, NN);
}

// Round 5
// 454.751 us; speedup vs baseline: 1.7768x; 1.2302x over previous
//
#include <hip/hip_runtime.h>

#define NN 50000
#define NE 800000
#define FIN 500
#define DH 128
#define NC 10

typedef __attribute__((ext_vector_type(8))) short short8v;   // 8 bf16 (4 VGPRs)
typedef __attribute__((ext_vector_type(4))) float float4v;   // MFMA C/D
typedef __attribute__((ext_vector_type(4))) int int4v;

__device__ __forceinline__ ushort f32_bf16_rne(float f) {
    uint u = __float_as_uint(f);
    uint r = u + 0x7FFFu + ((u >> 16) & 1u);
    return (ushort)(r >> 16);
}

// split 8 f32 -> bf16 hi + bf16 lo via v_cvt_pk_bf16_f32 (RNE, 2 elems/inst)
__device__ __forceinline__ void split8(const float f[8], short8v& hi, short8v& lo) {
    int4v hw, lw;
    #pragma unroll
    for (int p = 0; p < 4; ++p) {
        float x0 = f[2 * p], x1 = f[2 * p + 1];
        uint h;
        asm("v_cvt_pk_bf16_f32 %0, %1, %2" : "=v"(h) : "v"(x0), "v"(x1));
        float r0 = x0 - __uint_as_float(h << 16);
        float r1 = x1 - __uint_as_float(h & 0xFFFF0000u);
        uint l;
        asm("v_cvt_pk_bf16_f32 %0, %1, %2" : "=v"(l) : "v"(r0), "v"(r1));
        hw[p] = (int)h; lw[p] = (int)l;
    }
    hi = __builtin_bit_cast(short8v, hw);
    lo = __builtin_bit_cast(short8v, lw);
}

// ---------------- setup kernels ----------------

__global__ void init_kernel(float* __restrict__ deg, int* __restrict__ count, int n) {
    int i = blockIdx.x * blockDim.x + threadIdx.x;
    if (i < n) { deg[i] = 1.0f; count[i] = 0; }   // deg starts at 1.0 (self-loop weight)
}

__global__ void deg_count_kernel(const int* __restrict__ ei, const float* __restrict__ w,
                                 float* __restrict__ deg, int* __restrict__ count, int e) {
    int i = blockIdx.x * blockDim.x + threadIdx.x;
    if (i < e) {
        int d = ei[NE + i];               // dst row of edge_index
        atomicAdd(&deg[d], w[i]);
        atomicAdd(&count[d], 1);
    }
}

__global__ void dinv_kernel(float* __restrict__ deg, int n) {
    int i = blockIdx.x * blockDim.x + threadIdx.x;
    if (i < n) deg[i] = rsqrtf(deg[i]);   // deg >= 1 always (self-loop), in-place -> dinv
}

// ---- 3-phase scan: count[n] -> rowptr (exclusive), cursor copy ----
__global__ void scan1_kernel(const int* __restrict__ count, int* __restrict__ rp,
                             int* __restrict__ bsum, int n) {
    __shared__ int sw[4];
    int t = threadIdx.x, lane = t & 63, w = t >> 6;
    int base = blockIdx.x * 1024 + t * 4;
    int c0 = (base + 0 < n) ? count[base + 0] : 0;
    int c1 = (base + 1 < n) ? count[base + 1] : 0;
    int c2 = (base + 2 < n) ? count[base + 2] : 0;
    int c3 = (base + 3 < n) ? count[base + 3] : 0;
    int s0 = c0, s1 = s0 + c1, s2 = s1 + c2, s3 = s2 + c3;
    int x = s3;
    #pragma unroll
    for (int off = 1; off < 64; off <<= 1) {
        int y = __shfl_up(x, off, 64);
        if (lane >= off) x += y;
    }
    if (lane == 63) sw[w] = x;
    __syncthreads();
    int woff = 0;
    for (int j = 0; j < w; ++j) woff += sw[j];
    int excl = woff + x - s3;
    if (base + 0 < n) rp[base + 0] = excl;
    if (base + 1 < n) rp[base + 1] = excl + s0;
    if (base + 2 < n) rp[base + 2] = excl + s1;
    if (base + 3 < n) rp[base + 3] = excl + s2;
    if (t == 255) bsum[blockIdx.x] = woff + x;
}

__global__ void scan2_kernel(int* __restrict__ bsum, int nb) {
    int lane = threadIdx.x;
    int v = (lane < nb) ? bsum[lane] : 0;
    int x = v;
    #pragma unroll
    for (int off = 1; off < 64; off <<= 1) {
        int y = __shfl_up(x, off, 64);
        if (lane >= off) x += y;
    }
    if (lane < nb) bsum[lane] = x - v;
}

__global__ void scan3_kernel(int* __restrict__ rp, int* __restrict__ cursor,
                             const int* __restrict__ bsum, int n) {
    int i = blockIdx.x * blockDim.x + threadIdx.x;
    if (i < n) {
        int v = rp[i] + bsum[i >> 10];
        rp[i] = v;
        cursor[i] = v;
    }
    if (i == 0) rp[n] = NE;
}

__global__ void scatter_kernel(const int* __restrict__ ei, const float* __restrict__ w,
                               const float* __restrict__ dinv, int* __restrict__ cursor,
                               int* __restrict__ csr_src, float* __restrict__ csr_norm, int e) {
    int i = blockIdx.x * blockDim.x + threadIdx.x;
    if (i < e) {
        int s = ei[i];
        int d = ei[NE + i];
        int pos = atomicAdd(&cursor[d], 1);
        csr_src[pos] = s;
        csr_norm[pos] = dinv[s] * w[i] * dinv[d];
    }
}

// ---- prep: W[K][128] -> Bf in MFMA fragment order ----
// Bf element layout: idx = (((ks*8 + c)*2 + h)*64 + lane)*8 + j
//   value = split_{h}( W[k][col] ), k = ks*32 + (lane>>4)*8 + j, col = c*16 + (lane&15)
//   zero-padded for k >= K. Total = nks*8192 ushorts.
__global__ void prep_w_kernel(const float* __restrict__ W, ushort* __restrict__ Bf,
                              int K, int total) {
    int idx = blockIdx.x * blockDim.x + threadIdx.x;
    if (idx >= total) return;
    int j = idx & 7;
    int lane = (idx >> 3) & 63;
    int h = (idx >> 9) & 1;
    int c = (idx >> 10) & 7;
    int ks = idx >> 13;
    int k = ks * 32 + (lane >> 4) * 8 + j;
    int col = c * 16 + (lane & 15);
    float v = (k < K) ? W[k * DH + col] : 0.f;
    ushort hi = f32_bf16_rne(v);
    ushort o;
    if (h == 0) o = hi;
    else {
        float hf = __uint_as_float((uint)hi << 16);
        o = f32_bf16_rne(v - hf);
    }
    Bf[idx] = o;
}

// ---------------- MFMA matmul: C[M][128] = A[M][K] @ B[K][128] -------------
// bf16x3 split product, fp32 accumulate.
// Block: 256 thr = 4 waves, 128 rows (32/wave), all 128 cols.
// B chunk (BK=128) staged in LDS in fragment order: lane-contiguous b128 reads.

__device__ __forceinline__ void load_split_row(const float* __restrict__ Af, int row, int kb,
                                               int K, bool last, short8v& hi, short8v& lo) {
    float f[8];
    if (last && kb + 8 > K) {
        #pragma unroll
        for (int j = 0; j < 8; ++j)
            f[j] = (kb + j < K) ? Af[(size_t)row * K + kb + j] : 0.f;
    } else {
        // row stride K=500 is a multiple of 4 and kb%8==0 -> 16B aligned
        float4 t0 = *(const float4*)(Af + (size_t)row * K + kb);
        float4 t1 = *(const float4*)(Af + (size_t)row * K + kb + 4);
        f[0] = t0.x; f[1] = t0.y; f[2] = t0.z; f[3] = t0.w;
        f[4] = t1.x; f[5] = t1.y; f[6] = t1.z; f[7] = t1.w;
    }
    split8(f, hi, lo);
}

template<int A_SPLIT>
__global__ __launch_bounds__(256)
void mm_mfma_kernel(const float* __restrict__ Af,
                    const ushort* __restrict__ Ah, const ushort* __restrict__ Al,
                    const ushort* __restrict__ Bf,
                    float* __restrict__ C, int M, int K, int Kp) {
    __shared__ ushort Bs[4 * 8192];          // 64 KB: 4 ks x 8 c x 2 h x 64 lanes x 8
    const int t = threadIdx.x;
    const int lane = t & 63, wid = t >> 6;
    const int lrow = lane & 15, lk = lane >> 4;
    const int row0 = blockIdx.x * 128 + wid * 32;
    const int nchunks = Kp >> 7;             // Kp is a multiple of 128

    float4v acc0[8], acc1[8];
    #pragma unroll
    for (int c = 0; c < 8; ++c) {
        acc0[c] = (float4v){0.f, 0.f, 0.f, 0.f};
        acc1[c] = (float4v){0.f, 0.f, 0.f, 0.f};
    }

    int ar0 = row0 + lrow;       if (ar0 > M - 1) ar0 = M - 1;
    int ar1 = row0 + 16 + lrow;  if (ar1 > M - 1) ar1 = M - 1;
    const bool l0 = (ar0 == M - 1), l1 = (ar1 == M - 1);

    for (int kc = 0; kc < nchunks; ++kc) {
        // stage 64KB of B fragments: linear copy, coalesced
        const uint4* src = (const uint4*)(Bf + (size_t)kc * 32768);
        #pragma unroll
        for (int i = 0; i < 16; ++i) {
            int slot = i * 256 + t;
            *(uint4*)&Bs[slot * 8] = src[slot];
        }
        __syncthreads();
        #pragma unroll
        for (int ksl = 0; ksl < 4; ++ksl) {
            const int kb = (kc * 4 + ksl) * 32 + lk * 8;
            short8v a0h, a0l, a1h, a1l;
            if (A_SPLIT) {
                a0h = *(const short8v*)(Ah + (size_t)ar0 * Kp + kb);
                a0l = *(const short8v*)(Al + (size_t)ar0 * Kp + kb);
                a1h = *(const short8v*)(Ah + (size_t)ar1 * Kp + kb);
                a1l = *(const short8v*)(Al + (size_t)ar1 * Kp + kb);
            } else {
                load_split_row(Af, ar0, kb, K, l0, a0h, a0l);
                load_split_row(Af, ar1, kb, K, l1, a1h, a1l);
            }
            const ushort* bp = &Bs[ksl * 8192 + lane * 8];
            #pragma unroll
            for (int c = 0; c < 8; ++c) {
                short8v bh = *(const short8v*)(bp + c * 1024);
                short8v bl = *(const short8v*)(bp + c * 1024 + 512);
                acc0[c] = __builtin_amdgcn_mfma_f32_16x16x32_bf16(a0h, bh, acc0[c], 0, 0, 0);
                acc0[c] = __builtin_amdgcn_mfma_f32_16x16x32_bf16(a0h, bl, acc0[c], 0, 0, 0);
                acc0[c] = __builtin_amdgcn_mfma_f32_16x16x32_bf16(a0l, bh, acc0[c], 0, 0, 0);
                acc1[c] = __builtin_amdgcn_mfma_f32_16x16x32_bf16(a1h, bh, acc1[c], 0, 0, 0);
                acc1[c] = __builtin_amdgcn_mfma_f32_16x16x32_bf16(a1h, bl, acc1[c], 0, 0, 0);
                acc1[c] = __builtin_amdgcn_mfma_f32_16x16x32_bf16(a1l, bh, acc1[c], 0, 0, 0);
            }
        }
        __syncthreads();
    }
    // C/D layout: lane holds D[row=(lane>>4)*4+reg][col=lane&15]   [m89-verified]
    #pragma unroll
    for (int c = 0; c < 8; ++c) {
        #pragma unroll
        for (int j = 0; j < 4; ++j) {
            int r0 = row0 + lk * 4 + j;
            int r1 = row0 + 16 + lk * 4 + j;
            if (r0 < M) C[(size_t)r0 * DH + c * 16 + lrow] = acc0[c][j];
            if (r1 < M) C[(size_t)r1 * DH + c * 16 + lrow] = acc1[c][j];
        }
    }
}

// ---------------- aggregation: wave per node, float2 per lane ----------------
// out (layer1) written as bf16 hi/lo so mm2 skips conversion.

__global__ __launch_bounds__(256)
void agg_bf16_kernel(const float* __restrict__ h, const int* __restrict__ rowptr,
                     const int* __restrict__ csr_src, const float* __restrict__ csr_norm,
                     const float* __restrict__ dinv, const float* __restrict__ bias,
                     ushort* __restrict__ oh, ushort* __restrict__ ol, int n) {
    int node = (blockIdx.x * 256 + threadIdx.x) >> 6;
    if (node >= n) return;
    int lane = threadIdx.x & 63;
    float di = dinv[node];
    float2 hv = *(const float2*)&h[node * DH + lane * 2];
    float ax = di * di * hv.x, ay = di * di * hv.y;
    int e = rowptr[node], e1 = rowptr[node + 1];
    for (; e + 4 <= e1; e += 4) {
        int s0 = csr_src[e], s1 = csr_src[e + 1], s2 = csr_src[e + 2], s3 = csr_src[e + 3];
        float n0 = csr_norm[e], n1 = csr_norm[e + 1], n2 = csr_norm[e + 2], n3 = csr_norm[e + 3];
        float2 v0 = *(const float2*)&h[s0 * DH + lane * 2];
        float2 v1 = *(const float2*)&h[s1 * DH + lane * 2];
        float2 v2 = *(const float2*)&h[s2 * DH + lane * 2];
        float2 v3 = *(const float2*)&h[s3 * DH + lane * 2];
        ax = fmaf(n0, v0.x, ax); ay = fmaf(n0, v0.y, ay);
        ax = fmaf(n1, v1.x, ax); ay = fmaf(n1, v1.y, ay);
        ax = fmaf(n2, v2.x, ax); ay = fmaf(n2, v2.y, ay);
        ax = fmaf(n3, v3.x, ax); ay = fmaf(n3, v3.y, ay);
    }
    for (; e < e1; ++e) {
        int s = csr_src[e];
        float nm = csr_norm[e];
        float2 v = *(const float2*)&h[s * DH + lane * 2];
        ax = fmaf(nm, v.x, ax); ay = fmaf(nm, v.y, ay);
    }
    float hx = fmaxf(ax + bias[lane * 2], 0.f);
    float hy = fmaxf(ay + bias[lane * 2 + 1], 0.f);
    ushort hxh = f32_bf16_rne(hx);
    ushort hyh = f32_bf16_rne(hy);
    ushort hxl = f32_bf16_rne(hx - __uint_as_float((uint)hxh << 16));
    ushort hyl = f32_bf16_rne(hy - __uint_as_float((uint)hyh << 16));
    *(ushort2*)&oh[node * DH + lane * 2] = make_ushort2(hxh, hyh);
    *(ushort2*)&ol[node * DH + lane * 2] = make_ushort2(hxl, hyl);
}

// agg + classifier fused: h2 row stays in registers, out = relu(agg) @ Wc + bc
__global__ __launch_bounds__(256)
void agg_cls_kernel(const float* __restrict__ h, const int* __restrict__ rowptr,
                    const int* __restrict__ csr_src, const float* __restrict__ csr_norm,
                    const float* __restrict__ dinv, const float* __restrict__ bias,
                    const float* __restrict__ Wc, const float* __restrict__ bc,
                    float* __restrict__ out, int n) {
    int node = (blockIdx.x * 256 + threadIdx.x) >> 6;
    if (node >= n) return;
    int lane = threadIdx.x & 63;
    float di = dinv[node];
    float2 hv = *(const float2*)&h[node * DH + lane * 2];
    float ax = di * di * hv.x, ay = di * di * hv.y;
    int e = rowptr[node], e1 = rowptr[node + 1];
    for (; e + 4 <= e1; e += 4) {
        int s0 = csr_src[e], s1 = csr_src[e + 1], s2 = csr_src[e + 2], s3 = csr_src[e + 3];
        float n0 = csr_norm[e], n1 = csr_norm[e + 1], n2 = csr_norm[e + 2], n3 = csr_norm[e + 3];
        float2 v0 = *(const float2*)&h[s0 * DH + lane * 2];
        float2 v1 = *(const float2*)&h[s1 * DH + lane * 2];
        float2 v2 = *(const float2*)&h[s2 * DH + lane * 2];
        float2 v3 = *(const float2*)&h[s3 * DH + lane * 2];
        ax = fmaf(n0, v0.x, ax); ay = fmaf(n0, v0.y, ay);
        ax = fmaf(n1, v1.x, ax); ay = fmaf(n1, v1.y, ay);
        ax = fmaf(n2, v2.x, ax); ay = fmaf(n2, v2.y, ay);
        ax = fmaf(n3, v3.x, ax); ay = fmaf(n3, v3.y, ay);
    }
    for (; e < e1; ++e) {
        int s = csr_src[e];
        float nm = csr_norm[e];
        float2 v = *(const float2*)&h[s * DH + lane * 2];
        ax = fmaf(nm, v.x, ax); ay = fmaf(nm, v.y, ay);
    }
    float hx = fmaxf(ax + bias[lane * 2], 0.f);
    float hy = fmaxf(ay + bias[lane * 2 + 1], 0.f);
    float myv = 0.f;
    #pragma unroll
    for (int c = 0; c < NC; ++c) {
        float p = hx * Wc[(2 * lane) * NC + c] + hy * Wc[(2 * lane + 1) * NC + c];
        p += __shfl_xor(p, 32, 64);
        p += __shfl_xor(p, 16, 64);
        p += __shfl_xor(p, 8, 64);
        p += __shfl_xor(p, 4, 64);
        p += __shfl_xor(p, 2, 64);
        p += __shfl_xor(p, 1, 64);
        if (lane == c) myv = p;
    }
    if (lane < NC) out[node * NC + lane] = myv + bc[lane];
}

// ---------------- launch ----------------

extern "C" void kernel_launch(void* const* d_in, const int* in_sizes, int n_in,
                              void* d_out, int out_size, void* d_ws, size_t ws_size,
                              hipStream_t stream) {
    const float* x  = (const float*)d_in[0];
    const int*   ei = (const int*)d_in[1];
    const float* ew = (const float*)d_in[2];
    const float* W1 = (const float*)d_in[3];
    const float* b1 = (const float*)d_in[4];
    const float* W2 = (const float*)d_in[5];
    const float* b2 = (const float*)d_in[6];
    const float* Wc = (const float*)d_in[7];
    const float* bc = (const float*)d_in[8];
    float* out = (float*)d_out;

    char* ws = (char*)d_ws;
    size_t off = 0;
    auto alloc = [&](size_t bytes) { char* p = ws + off; off += (bytes + 255) & ~255ULL; return p; };
    float*  deg      = (float*)alloc(NN * 4);        // becomes dinv in-place
    int*    count    = (int*)  alloc(NN * 4);
    int*    rowptr   = (int*)  alloc((NN + 1) * 4);
    int*    cursor   = (int*)  alloc(NN * 4);
    int*    bsum     = (int*)  alloc(64 * 4);
    int*    csr_src  = (int*)  alloc(NE * 4);
    float*  csr_norm = (float*)alloc(NE * 4);
    ushort* Bf1      = (ushort*)alloc(16 * 8192 * 2);   // K=512 fragments (hi/lo)
    ushort* Bf2      = (ushort*)alloc(4 * 8192 * 2);    // K=128 fragments
    float*  P0       = (float*)alloc((size_t)NN * DH * 4);
    ushort* H2h      = (ushort*)alloc((size_t)NN * DH * 2);
    ushort* H2l      = (ushort*)alloc((size_t)NN * DH * 2);

    init_kernel<<<(NN + 255) / 256, 256, 0, stream>>>(deg, count, NN);
    deg_count_kernel<<<(NE + 255) / 256, 256, 0, stream>>>(ei, ew, deg, count, NE);
    dinv_kernel<<<(NN + 255) / 256, 256, 0, stream>>>(deg, NN);
    scan1_kernel<<<(NN + 1023) / 1024, 256, 0, stream>>>(count, rowptr, bsum, NN);
    scan2_kernel<<<1, 64, 0, stream>>>(bsum, (NN + 1023) / 1024);
    scan3_kernel<<<(NN + 255) / 256, 256, 0, stream>>>(rowptr, cursor, bsum, NN);
    scatter_kernel<<<(NE + 255) / 256, 256, 0, stream>>>(ei, ew, deg, cursor, csr_src, csr_norm, NE);
    prep_w_kernel<<<(16 * 8192 + 255) / 256, 256, 0, stream>>>(W1, Bf1, FIN, 16 * 8192);
    prep_w_kernel<<<(4 * 8192 + 255) / 256, 256, 0, stream>>>(W2, Bf2, DH, 4 * 8192);

    int mm_blocks = (NN + 127) / 128;   // 391

    // layer 1: h1 = x @ W1 (MFMA bf16x3, in-reg split of A), agg -> bf16 hi/lo
    mm_mfma_kernel<0><<<mm_blocks, 256, 0, stream>>>(x, nullptr, nullptr, Bf1, P0, NN, FIN, 512);
    agg_bf16_kernel<<<(NN * 64 + 255) / 256, 256, 0, stream>>>(P0, rowptr, csr_src, csr_norm,
                                                               deg, b1, H2h, H2l, NN);
    // layer 2: h2 = h1 @ W2 (A pre-split), fused agg+relu+classifier
    mm_mfma_kernel<1><<<mm_blocks, 256, 0, stream>>>(nullptr, H2h, H2l, Bf2, P0, NN, DH, 128);
    agg_cls_kernel<<<(NN * 64 + 255) / 256, 256, 0, stream>>>(P0, rowptr, csr_src, csr_norm,
                                                              deg, b2, Wc, bc, out, NN);
}

// Round 8
// 403.705 us; speedup vs baseline: 2.0015x; 1.1264x over previous
//
#include <hip/hip_runtime.h>

#define NN 50000
#define NE 800000
#define FIN 500
#define DH 128
#define NC 10

typedef __attribute__((ext_vector_type(8))) short short8v;   // 8 bf16 (4 VGPRs)
typedef __attribute__((ext_vector_type(4))) float float4v;   // MFMA C/D
typedef __attribute__((ext_vector_type(4))) int int4v;

__device__ __forceinline__ ushort f32_bf16_rne(float f) {
    uint u = __float_as_uint(f);
    uint r = u + 0x7FFFu + ((u >> 16) & 1u);
    return (ushort)(r >> 16);
}

// split 8 f32 -> bf16 hi + bf16 lo via v_cvt_pk_bf16_f32 (RNE, 2 elems/inst)
__device__ __forceinline__ void split8(const float f[8], short8v& hi, short8v& lo) {
    int4v hw, lw;
    #pragma unroll
    for (int p = 0; p < 4; ++p) {
        float x0 = f[2 * p], x1 = f[2 * p + 1];
        uint h;
        asm("v_cvt_pk_bf16_f32 %0, %1, %2" : "=v"(h) : "v"(x0), "v"(x1));
        float r0 = x0 - __uint_as_float(h << 16);
        float r1 = x1 - __uint_as_float(h & 0xFFFF0000u);
        uint l;
        asm("v_cvt_pk_bf16_f32 %0, %1, %2" : "=v"(l) : "v"(r0), "v"(r1));
        hw[p] = (int)h; lw[p] = (int)l;
    }
    hi = __builtin_bit_cast(short8v, hw);
    lo = __builtin_bit_cast(short8v, lw);
}

// ---------------- setup kernels ----------------

__global__ void init_packed_kernel(unsigned long long* __restrict__ packed, int n) {
    int i = blockIdx.x * blockDim.x + threadIdx.x;
    if (i < n) packed[i] = 0ULL;
}

// ONE 64-bit atomic per edge: high word = incoming-edge count, low word = sum of
// w in 24-bit fixed point (max ~50 edges * 2^24 < 2^31: no carry into count).
// Returned old high word = this edge's rank within its dst row.
__global__ void deg_rank_kernel(const int* __restrict__ ei, const float* __restrict__ w,
                                unsigned long long* __restrict__ packed,
                                uint* __restrict__ rank, int e) {
    int i = blockIdx.x * blockDim.x + threadIdx.x;
    if (i < e) {
        int d = ei[NE + i];
        uint fx = (uint)(w[i] * 16777216.0f + 0.5f);
        unsigned long long old = atomicAdd(&packed[d], (1ULL << 32) | (unsigned long long)fx);
        rank[i] = (uint)(old >> 32);
    }
}

// deg = 1 (self-loop) + fixed-point sum; dinv = rsqrt(deg)
__global__ void unpack_kernel(const unsigned long long* __restrict__ packed,
                              float* __restrict__ dinv, int n) {
    int i = blockIdx.x * blockDim.x + threadIdx.x;
    if (i < n) {
        float deg = 1.0f + (float)(uint)packed[i] * (1.0f / 16777216.0f);
        dinv[i] = rsqrtf(deg);
    }
}

// ---- 3-phase scan over counts (high words of packed) -> rowptr (exclusive) ----
__global__ void scan1_kernel(const unsigned long long* __restrict__ packed,
                             int* __restrict__ rp, int* __restrict__ bsum, int n) {
    __shared__ int sw[4];
    int t = threadIdx.x, lane = t & 63, w = t >> 6;
    int base = blockIdx.x * 1024 + t * 4;
    int c0 = (base + 0 < n) ? (int)(packed[base + 0] >> 32) : 0;
    int c1 = (base + 1 < n) ? (int)(packed[base + 1] >> 32) : 0;
    int c2 = (base + 2 < n) ? (int)(packed[base + 2] >> 32) : 0;
    int c3 = (base + 3 < n) ? (int)(packed[base + 3] >> 32) : 0;
    int s0 = c0, s1 = s0 + c1, s2 = s1 + c2, s3 = s2 + c3;
    int x = s3;
    #pragma unroll
    for (int off = 1; off < 64; off <<= 1) {
        int y = __shfl_up(x, off, 64);
        if (lane >= off) x += y;
    }
    if (lane == 63) sw[w] = x;
    __syncthreads();
    int woff = 0;
    for (int j = 0; j < w; ++j) woff += sw[j];
    int excl = woff + x - s3;
    if (base + 0 < n) rp[base + 0] = excl;
    if (base + 1 < n) rp[base + 1] = excl + s0;
    if (base + 2 < n) rp[base + 2] = excl + s1;
    if (base + 3 < n) rp[base + 3] = excl + s2;
    if (t == 255) bsum[blockIdx.x] = woff + x;
}

__global__ void scan2_kernel(int* __restrict__ bsum, int nb) {
    int lane = threadIdx.x;
    int v = (lane < nb) ? bsum[lane] : 0;
    int x = v;
    #pragma unroll
    for (int off = 1; off < 64; off <<= 1) {
        int y = __shfl_up(x, off, 64);
        if (lane >= off) x += y;
    }
    if (lane < nb) bsum[lane] = x - v;
}

__global__ void scan3_kernel(int* __restrict__ rp, const int* __restrict__ bsum, int n) {
    int i = blockIdx.x * blockDim.x + threadIdx.x;
    if (i < n) rp[i] = rp[i] + bsum[i >> 10];
    if (i == 0) rp[n] = NE;
}

// atomic-free scatter: pos = rowptr[d] + rank
__global__ void scatter_kernel(const int* __restrict__ ei, const float* __restrict__ w,
                               const float* __restrict__ dinv, const uint* __restrict__ rank,
                               const int* __restrict__ rowptr,
                               int* __restrict__ csr_src, float* __restrict__ csr_norm, int e) {
    int i = blockIdx.x * blockDim.x + threadIdx.x;
    if (i < e) {
        int s = ei[i];
        int d = ei[NE + i];
        int pos = rowptr[d] + (int)rank[i];
        csr_src[pos] = s;
        csr_norm[pos] = dinv[s] * w[i] * dinv[d];
    }
}

// ---- prep: W[K][128] -> Bf in MFMA fragment order ----
// Bf element layout: idx = (((ks*8 + c)*2 + h)*64 + lane)*8 + j
//   value = split_{h}( W[k][col] ), k = ks*32 + (lane>>4)*8 + j, col = c*16 + (lane&15)
//   zero-padded for k >= K. Total = nks*8192 ushorts.
__global__ void prep_w_kernel(const float* __restrict__ W, ushort* __restrict__ Bf,
                              int K, int total) {
    int idx = blockIdx.x * blockDim.x + threadIdx.x;
    if (idx >= total) return;
    int j = idx & 7;
    int lane = (idx >> 3) & 63;
    int h = (idx >> 9) & 1;
    int c = (idx >> 10) & 7;
    int ks = idx >> 13;
    int k = ks * 32 + (lane >> 4) * 8 + j;
    int col = c * 16 + (lane & 15);
    float v = (k < K) ? W[k * DH + col] : 0.f;
    ushort hi = f32_bf16_rne(v);
    ushort o;
    if (h == 0) o = hi;
    else {
        float hf = __uint_as_float((uint)hi << 16);
        o = f32_bf16_rne(v - hf);
    }
    Bf[idx] = o;
}

// ---------------- MFMA matmul: C[M][128] = A[M][K] @ B[K][128] -------------
// bf16x3 split product, fp32 accumulate.
// Block: 256 thr = 4 waves, 128 rows (32/wave), all 128 cols.
// B chunk (BK=128) staged in LDS in fragment order: lane-contiguous b128 reads.

__device__ __forceinline__ void load_split_row(const float* __restrict__ Af, int row, int kb,
                                               int K, bool last, short8v& hi, short8v& lo) {
    float f[8];
    if (last && kb + 8 > K) {
        #pragma unroll
        for (int j = 0; j < 8; ++j)
            f[j] = (kb + j < K) ? Af[(size_t)row * K + kb + j] : 0.f;
    } else {
        // row stride K=500 is a multiple of 4 and kb%8==0 -> 16B aligned
        float4 t0 = *(const float4*)(Af + (size_t)row * K + kb);
        float4 t1 = *(const float4*)(Af + (size_t)row * K + kb + 4);
        f[0] = t0.x; f[1] = t0.y; f[2] = t0.z; f[3] = t0.w;
        f[4] = t1.x; f[5] = t1.y; f[6] = t1.z; f[7] = t1.w;
    }
    split8(f, hi, lo);
}

template<int A_SPLIT>
__global__ __launch_bounds__(256)
void mm_mfma_kernel(const float* __restrict__ Af,
                    const ushort* __restrict__ Ah, const ushort* __restrict__ Al,
                    const ushort* __restrict__ Bf,
                    float* __restrict__ C, int M, int K, int Kp) {
    __shared__ ushort Bs[4 * 8192];          // 64 KB: 4 ks x 8 c x 2 h x 64 lanes x 8
    const int t = threadIdx.x;
    const int lane = t & 63, wid = t >> 6;
    const int lrow = lane & 15, lk = lane >> 4;
    const int row0 = blockIdx.x * 128 + wid * 32;
    const int nchunks = Kp >> 7;             // Kp is a multiple of 128

    float4v acc0[8], acc1[8];
    #pragma unroll
    for (int c = 0; c < 8; ++c) {
        acc0[c] = (float4v){0.f, 0.f, 0.f, 0.f};
        acc1[c] = (float4v){0.f, 0.f, 0.f, 0.f};
    }

    int ar0 = row0 + lrow;       if (ar0 > M - 1) ar0 = M - 1;
    int ar1 = row0 + 16 + lrow;  if (ar1 > M - 1) ar1 = M - 1;
    const bool l0 = (ar0 == M - 1), l1 = (ar1 == M - 1);

    for (int kc = 0; kc < nchunks; ++kc) {
        // stage 64KB of B fragments: linear copy, coalesced
        const uint4* src = (const uint4*)(Bf + (size_t)kc * 32768);
        #pragma unroll
        for (int i = 0; i < 16; ++i) {
            int slot = i * 256 + t;
            *(uint4*)&Bs[slot * 8] = src[slot];
        }
        __syncthreads();
        #pragma unroll
        for (int ksl = 0; ksl < 4; ++ksl) {
            const int kb = (kc * 4 + ksl) * 32 + lk * 8;
            short8v a0h, a0l, a1h, a1l;
            if (A_SPLIT) {
                a0h = *(const short8v*)(Ah + (size_t)ar0 * Kp + kb);
                a0l = *(const short8v*)(Al + (size_t)ar0 * Kp + kb);
                a1h = *(const short8v*)(Ah + (size_t)ar1 * Kp + kb);
                a1l = *(const short8v*)(Al + (size_t)ar1 * Kp + kb);
            } else {
                load_split_row(Af, ar0, kb, K, l0, a0h, a0l);
                load_split_row(Af, ar1, kb, K, l1, a1h, a1l);
            }
            const ushort* bp = &Bs[ksl * 8192 + lane * 8];
            #pragma unroll
            for (int c = 0; c < 8; ++c) {
                short8v bh = *(const short8v*)(bp + c * 1024);
                short8v bl = *(const short8v*)(bp + c * 1024 + 512);
                acc0[c] = __builtin_amdgcn_mfma_f32_16x16x32_bf16(a0h, bh, acc0[c], 0, 0, 0);
                acc0[c] = __builtin_amdgcn_mfma_f32_16x16x32_bf16(a0h, bl, acc0[c], 0, 0, 0);
                acc0[c] = __builtin_amdgcn_mfma_f32_16x16x32_bf16(a0l, bh, acc0[c], 0, 0, 0);
                acc1[c] = __builtin_amdgcn_mfma_f32_16x16x32_bf16(a1h, bh, acc1[c], 0, 0, 0);
                acc1[c] = __builtin_amdgcn_mfma_f32_16x16x32_bf16(a1h, bl, acc1[c], 0, 0, 0);
                acc1[c] = __builtin_amdgcn_mfma_f32_16x16x32_bf16(a1l, bh, acc1[c], 0, 0, 0);
            }
        }
        __syncthreads();
    }
    // C/D layout: lane holds D[row=(lane>>4)*4+reg][col=lane&15]   [m89-verified]
    #pragma unroll
    for (int c = 0; c < 8; ++c) {
        #pragma unroll
        for (int j = 0; j < 4; ++j) {
            int r0 = row0 + lk * 4 + j;
            int r1 = row0 + 16 + lk * 4 + j;
            if (r0 < M) C[(size_t)r0 * DH + c * 16 + lrow] = acc0[c][j];
            if (r1 < M) C[(size_t)r1 * DH + c * 16 + lrow] = acc1[c][j];
        }
    }
}

// ---------------- aggregation: wave per node, float2 per lane ----------------
// out (layer1) written as bf16 hi/lo so mm2 skips conversion.

__global__ __launch_bounds__(256)
void agg_bf16_kernel(const float* __restrict__ h, const int* __restrict__ rowptr,
                     const int* __restrict__ csr_src, const float* __restrict__ csr_norm,
                     const float* __restrict__ dinv, const float* __restrict__ bias,
                     ushort* __restrict__ oh, ushort* __restrict__ ol, int n) {
    int node = (blockIdx.x * 256 + threadIdx.x) >> 6;
    if (node >= n) return;
    int lane = threadIdx.x & 63;
    float di = dinv[node];
    float2 hv = *(const float2*)&h[node * DH + lane * 2];
    float ax = di * di * hv.x, ay = di * di * hv.y;
    int e = rowptr[node], e1 = rowptr[node + 1];
    for (; e + 4 <= e1; e += 4) {
        int s0 = csr_src[e], s1 = csr_src[e + 1], s2 = csr_src[e + 2], s3 = csr_src[e + 3];
        float n0 = csr_norm[e], n1 = csr_norm[e + 1], n2 = csr_norm[e + 2], n3 = csr_norm[e + 3];
        float2 v0 = *(const float2*)&h[s0 * DH + lane * 2];
        float2 v1 = *(const float2*)&h[s1 * DH + lane * 2];
        float2 v2 = *(const float2*)&h[s2 * DH + lane * 2];
        float2 v3 = *(const float2*)&h[s3 * DH + lane * 2];
        ax = fmaf(n0, v0.x, ax); ay = fmaf(n0, v0.y, ay);
        ax = fmaf(n1, v1.x, ax); ay = fmaf(n1, v1.y, ay);
        ax = fmaf(n2, v2.x, ax); ay = fmaf(n2, v2.y, ay);
        ax = fmaf(n3, v3.x, ax); ay = fmaf(n3, v3.y, ay);
    }
    for (; e < e1; ++e) {
        int s = csr_src[e];
        float nm = csr_norm[e];
        float2 v = *(const float2*)&h[s * DH + lane * 2];
        ax = fmaf(nm, v.x, ax); ay = fmaf(nm, v.y, ay);
    }
    float hx = fmaxf(ax + bias[lane * 2], 0.f);
    float hy = fmaxf(ay + bias[lane * 2 + 1], 0.f);
    ushort hxh = f32_bf16_rne(hx);
    ushort hyh = f32_bf16_rne(hy);
    ushort hxl = f32_bf16_rne(hx - __uint_as_float((uint)hxh << 16));
    ushort hyl = f32_bf16_rne(hy - __uint_as_float((uint)hyh << 16));
    *(ushort2*)&oh[node * DH + lane * 2] = make_ushort2(hxh, hyh);
    *(ushort2*)&ol[node * DH + lane * 2] = make_ushort2(hxl, hyl);
}

// agg + classifier fused: h2 row stays in registers, out = relu(agg) @ Wc + bc
__global__ __launch_bounds__(256)
void agg_cls_kernel(const float* __restrict__ h, const int* __restrict__ rowptr,
                    const int* __restrict__ csr_src, const float* __restrict__ csr_norm,
                    const float* __restrict__ dinv, const float* __restrict__ bias,
                    const float* __restrict__ Wc, const float* __restrict__ bc,
                    float* __restrict__ out, int n) {
    int node = (blockIdx.x * 256 + threadIdx.x) >> 6;
    if (node >= n) return;
    int lane = threadIdx.x & 63;
    float di = dinv[node];
    float2 hv = *(const float2*)&h[node * DH + lane * 2];
    float ax = di * di * hv.x, ay = di * di * hv.y;
    int e = rowptr[node], e1 = rowptr[node + 1];
    for (; e + 4 <= e1; e += 4) {
        int s0 = csr_src[e], s1 = csr_src[e + 1], s2 = csr_src[e + 2], s3 = csr_src[e + 3];
        float n0 = csr_norm[e], n1 = csr_norm[e + 1], n2 = csr_norm[e + 2], n3 = csr_norm[e + 3];
        float2 v0 = *(const float2*)&h[s0 * DH + lane * 2];
        float2 v1 = *(const float2*)&h[s1 * DH + lane * 2];
        float2 v2 = *(const float2*)&h[s2 * DH + lane * 2];
        float2 v3 = *(const float2*)&h[s3 * DH + lane * 2];
        ax = fmaf(n0, v0.x, ax); ay = fmaf(n0, v0.y, ay);
        ax = fmaf(n1, v1.x, ax); ay = fmaf(n1, v1.y, ay);
        ax = fmaf(n2, v2.x, ax); ay = fmaf(n2, v2.y, ay);
        ax = fmaf(n3, v3.x, ax); ay = fmaf(n3, v3.y, ay);
    }
    for (; e < e1; ++e) {
        int s = csr_src[e];
        float nm = csr_norm[e];
        float2 v = *(const float2*)&h[s * DH + lane * 2];
        ax = fmaf(nm, v.x, ax); ay = fmaf(nm, v.y, ay);
    }
    float hx = fmaxf(ax + bias[lane * 2], 0.f);
    float hy = fmaxf(ay + bias[lane * 2 + 1], 0.f);
    float myv = 0.f;
    #pragma unroll
    for (int c = 0; c < NC; ++c) {
        float p = hx * Wc[(2 * lane) * NC + c] + hy * Wc[(2 * lane + 1) * NC + c];
        p += __shfl_xor(p, 32, 64);
        p += __shfl_xor(p, 16, 64);
        p += __shfl_xor(p, 8, 64);
        p += __shfl_xor(p, 4, 64);
        p += __shfl_xor(p, 2, 64);
        p += __shfl_xor(p, 1, 64);
        if (lane == c) myv = p;
    }
    if (lane < NC) out[node * NC + lane] = myv + bc[lane];
}

// ---------------- launch ----------------

extern "C" void kernel_launch(void* const* d_in, const int* in_sizes, int n_in,
                              void* d_out, int out_size, void* d_ws, size_t ws_size,
                              hipStream_t stream) {
    const float* x  = (const float*)d_in[0];
    const int*   ei = (const int*)d_in[1];
    const float* ew = (const float*)d_in[2];
    const float* W1 = (const float*)d_in[3];
    const float* b1 = (const float*)d_in[4];
    const float* W2 = (const float*)d_in[5];
    const float* b2 = (const float*)d_in[6];
    const float* Wc = (const float*)d_in[7];
    const float* bc = (const float*)d_in[8];
    float* out = (float*)d_out;

    char* ws = (char*)d_ws;
    size_t off = 0;
    auto alloc = [&](size_t bytes) { char* p = ws + off; off += (bytes + 255) & ~255ULL; return p; };
    float*  dinv     = (float*)alloc(NN * 4);
    int*    rowptr   = (int*)  alloc((NN + 1) * 4);
    int*    bsum     = (int*)  alloc(64 * 4);
    int*    csr_src  = (int*)  alloc(NE * 4);
    float*  csr_norm = (float*)alloc(NE * 4);
    ushort* Bf1      = (ushort*)alloc(16 * 8192 * 2);   // K=512 fragments (hi/lo)
    ushort* Bf2      = (ushort*)alloc(4 * 8192 * 2);    // K=128 fragments
    float*  P0       = (float*)alloc((size_t)NN * DH * 4);
    ushort* H2h      = (ushort*)alloc((size_t)NN * DH * 2);
    ushort* H2l      = (ushort*)alloc((size_t)NN * DH * 2);

    // setup-phase aliases into regions dead until mm1/agg1:
    uint* rank = (uint*)P0;                                  // dead once mm1 writes P0
    unsigned long long* packed = (unsigned long long*)H2h;   // dead once agg1 writes H2h

    init_packed_kernel<<<(NN + 255) / 256, 256, 0, stream>>>(packed, NN);
    deg_rank_kernel<<<(NE + 255) / 256, 256, 0, stream>>>(ei, ew, packed, rank, NE);
    unpack_kernel<<<(NN + 255) / 256, 256, 0, stream>>>(packed, dinv, NN);
    scan1_kernel<<<(NN + 1023) / 1024, 256, 0, stream>>>(packed, rowptr, bsum, NN);
    scan2_kernel<<<1, 64, 0, stream>>>(bsum, (NN + 1023) / 1024);
    scan3_kernel<<<(NN + 255) / 256, 256, 0, stream>>>(rowptr, bsum, NN);
    scatter_kernel<<<(NE + 255) / 256, 256, 0, stream>>>(ei, ew, dinv, rank, rowptr,
                                                         csr_src, csr_norm, NE);
    prep_w_kernel<<<(16 * 8192 + 255) / 256, 256, 0, stream>>>(W1, Bf1, FIN, 16 * 8192);
    prep_w_kernel<<<(4 * 8192 + 255) / 256, 256, 0, stream>>>(W2, Bf2, DH, 4 * 8192);

    int mm_blocks = (NN + 127) / 128;   // 391

    // layer 1: h1 = x @ W1 (MFMA bf16x3, in-reg split of A), agg -> bf16 hi/lo
    mm_mfma_kernel<0><<<mm_blocks, 256, 0, stream>>>(x, nullptr, nullptr, Bf1, P0, NN, FIN, 512);
    agg_bf16_kernel<<<(NN * 64 + 255) / 256, 256, 0, stream>>>(P0, rowptr, csr_src, csr_norm,
                                                               dinv, b1, H2h, H2l, NN);
    // layer 2: h2 = h1 @ W2 (A pre-split), fused agg+relu+classifier
    mm_mfma_kernel<1><<<mm_blocks, 256, 0, stream>>>(nullptr, H2h, H2l, Bf2, P0, NN, DH, 128);
    agg_cls_kernel<<<(NN * 64 + 255) / 256, 256, 0, stream>>>(P0, rowptr, csr_src, csr_norm,
                                                              dinv, b2, Wc, bc, out, NN);
}